// Round 8
// baseline (19750.967 us; speedup 1.0000x reference)
//
#include <hip/hip_runtime.h>

// ---------------------------------------------------------------------------
// CVXProjLoss: batched QP interior-point projection.
// B=16, C=1000 (constraints m), F=256 (vars n), K=10, 20 IPM iters.
//
// Structure: D has <=2 nonzeros per row, so
//   G[b,c,:] = W[a_c] - W[b_c]   (a_c=b_c=0 => zero row for c == t0)
//   G z      = (W z)[a] - (W z)[b]
//   G^T v    = W^T u,  u = closed-form scatter of v
//   M        = 2I + sum_c w_c g_c g_c^T   (w applied inside SYRK; no sqrt)
// Solver: f64 LDL^T (no sqrt). R6 profile: k_chol = 58% of runtime,
// latency-bound (occ 1.4%, VALU 0.9%, 48 serial segments). R7/R8: NB=32
// (24 segments), 1024 threads (2x tile parallelism), u-only LDS panel,
// XOR bank swizzle.  (R8 == R7; R7 bench never ran - acquisition timeout.)
// ---------------------------------------------------------------------------

#define B_N 16
#define C_N 1000
#define F_N 256
#define ITERS_N 20
#define SIGMA_C 0.1f
#define BIGV 1e10f

// ws layout (float offsets)
static const size_t OFF_WT  = 0;                      // 256*1000
static const size_t OFF_X   = 256000;                 // 16*1000*256 (unweighted rows)
static const size_t OFF_M64 = 4352000;                // f64 16*256*256 (= 2097152 floats)
static const size_t OFF_H   = 6449152;                // 16*1000
static const size_t OFF_LAM = OFF_H   + 16000;
static const size_t OFF_S   = OFF_LAM + 16000;
static const size_t OFF_RP  = OFF_S   + 16000;
static const size_t OFF_RC  = OFF_RP  + 16000;
static const size_t OFF_WV  = OFF_RC  + 16000;        // w = lam/s
static const size_t OFF_Z   = OFF_WV  + 16000;        // 16*256
static const size_t OFF_DZ  = OFF_Z   + 4096;
static const size_t OFF_RHS = OFF_DZ  + 4096;
static const size_t OFF_AI  = OFF_RHS + 4096;         // int 16*1000
static const size_t OFF_BI  = OFF_AI  + 16000;        // int 16*1000
// end = OFF_BI + 16000 = 6,589,440 floats ~= 25.1 MiB

__device__ __forceinline__ float bsum256(float v, float* red) {
#pragma unroll
  for (int o = 32; o > 0; o >>= 1) v += __shfl_down(v, o);
  __syncthreads();
  if ((threadIdx.x & 63) == 0) red[threadIdx.x >> 6] = v;
  __syncthreads();
  return red[0] + red[1] + red[2] + red[3];
}
__device__ __forceinline__ float bmin256(float v, float* red) {
#pragma unroll
  for (int o = 32; o > 0; o >>= 1) v = fminf(v, __shfl_down(v, o));
  __syncthreads();
  if ((threadIdx.x & 63) == 0) red[threadIdx.x >> 6] = v;
  __syncthreads();
  return fminf(fminf(red[0], red[1]), fminf(red[2], red[3]));
}

// ---------------------------------------------------------------------------
// S1: WT[k][c] = W[c][k]   (64x64 LDS-tiled transpose)
__global__ __launch_bounds__(256) void k_transpose(const float* __restrict__ W,
                                                   float* __restrict__ WT) {
  __shared__ float tile[64][65];
  int tc = blockIdx.x & 15, tk = blockIdx.x >> 4;
  int c0 = tc * 64, k0 = tk * 64;
  int t = threadIdx.x;
  int jj = t & 63, r4 = t >> 6;
#pragma unroll
  for (int i = 0; i < 16; ++i) {
    int r = r4 + i * 4;
    int c = c0 + r;
    tile[r][jj] = (c < C_N) ? W[c * F_N + k0 + jj] : 0.f;
  }
  __syncthreads();
#pragma unroll
  for (int i = 0; i < 16; ++i) {
    int kr = r4 + i * 4;
    int cc = c0 + jj;
    if (cc < C_N) WT[(k0 + kr) * C_N + cc] = tile[jj][kr];
  }
}

// ---------------------------------------------------------------------------
// S2: build a_idx, b_idx, h; init lam=s=1, z=feats_pred
__global__ __launch_bounds__(256) void k_setup(const int* __restrict__ tg,
                                               const float* __restrict__ bias,
                                               const float* __restrict__ feats,
                                               const float* __restrict__ marg,
                                               float* wsf) {
  int b = blockIdx.x, t = threadIdx.x;
  __shared__ int tsh[10];
  if (t < 10) tsh[t] = tg[b * 10 + t];
  __syncthreads();
  float m = marg[0];
  int t9 = tsh[9];
  float bias_t9 = bias[t9];
  int*   ai  = (int*)(wsf + OFF_AI) + b * C_N;
  int*   bi  = (int*)(wsf + OFF_BI) + b * C_N;
  float* h   = wsf + OFF_H   + b * C_N;
  float* lam = wsf + OFF_LAM + b * C_N;
  float* s   = wsf + OFF_S   + b * C_N;
#pragma unroll
  for (int r = 0; r < 4; ++r) {
    int c = t + 256 * r;
    if (c < C_N) {
      int rk = -1;
#pragma unroll
      for (int i = 0; i < 10; ++i) if (c == tsh[i]) rk = i;
      int av, bv; float hv;
      if (rk < 0)       { av = c;        bv = t9;         hv = bias_t9 - bias[c] - m; }
      else if (rk == 0) { av = 0;        bv = 0;          hv = 0.f; }
      else              { av = tsh[rk];  bv = tsh[rk-1];  hv = bias[tsh[rk-1]] - bias[tsh[rk]] - m; }
      ai[c] = av; bi[c] = bv; h[c] = hv; lam[c] = 1.f; s[c] = 1.f;
    }
  }
  (wsf + OFF_Z)[b * F_N + t] = feats[b * F_N + t];
}

// ---------------------------------------------------------------------------
// K_B: X[b][c][k] = W[a_c][k] - W[b_c][k]  (UNWEIGHTED; runs ONCE).
__global__ __launch_bounds__(256) void k_buildX(const float* __restrict__ W,
                                                float* wsf) {
  int bb = blockIdx.x >> 3, part = blockIdx.x & 7;
  int t = threadIdx.x;
  __shared__ int aL[125], bL[125];
  int c0 = part * 125;
  const int* ai = (const int*)(wsf + OFF_AI) + bb * C_N;
  const int* bi = (const int*)(wsf + OFF_BI) + bb * C_N;
  if (t < 125) { aL[t] = ai[c0 + t]; bL[t] = bi[c0 + t]; }
  __syncthreads();
  float* X = wsf + OFF_X + (size_t)bb * 256000 + (size_t)c0 * F_N;
  for (int i = 0; i < 125; ++i) {
    float wa = W[aL[i] * F_N + t];
    float wb = W[bL[i] * F_N + t];
    X[i * F_N + t] = wa - wb;
  }
}

// ---------------------------------------------------------------------------
// K_A: apply previous step's update (if any), then residuals, w, scatter u,
// rhs = -(2z + p + W^T u).  One block per batch, 256 threads.
__global__ __launch_bounds__(256) void k_iter_pre(const float* __restrict__ W,
                                                  const float* __restrict__ feats,
                                                  const int* __restrict__ tg,
                                                  float* wsf, int do_update) {
  int b = blockIdx.x, t = threadIdx.x;
  __shared__ float zs[256], dzs[256];
  __shared__ __align__(16) float ys[1000];
  __shared__ float vs[1000];
  __shared__ float red[4];
  __shared__ int tsh[10];

  const float* WT = wsf + OFF_WT;
  const int* ai  = (const int*)(wsf + OFF_AI) + b * C_N;
  const int* bi  = (const int*)(wsf + OFF_BI) + b * C_N;
  float* h    = wsf + OFF_H   + b * C_N;
  float* lam  = wsf + OFF_LAM + b * C_N;
  float* s    = wsf + OFF_S   + b * C_N;
  float* rp   = wsf + OFF_RP  + b * C_N;
  float* rc   = wsf + OFF_RC  + b * C_N;
  float* wbuf = wsf + OFF_WV  + b * C_N;
  float* z    = wsf + OFF_Z   + b * F_N;
  float* dz   = wsf + OFF_DZ  + b * F_N;
  float* rhs  = wsf + OFF_RHS + b * F_N;

  if (t < 10) tsh[t] = tg[b * 10 + t];
  zs[t] = z[t];
  if (do_update) dzs[t] = dz[t];
  __syncthreads();

  float lamr[4], sr[4], rpr[4];
  if (do_update) {
    if (t < 250) {
      float4 acc = make_float4(0.f, 0.f, 0.f, 0.f);
      const float4* WT4 = (const float4*)WT;
#pragma unroll 4
      for (int k = 0; k < 256; ++k) {
        float zk = dzs[k];
        float4 w4 = WT4[k * 250 + t];
        acc.x += zk * w4.x; acc.y += zk * w4.y; acc.z += zk * w4.z; acc.w += zk * w4.w;
      }
      *(float4*)&ys[4 * t] = acc;
    }
    __syncthreads();
    float amin = BIGV;
    float dsr[4], dlr[4];
#pragma unroll
    for (int r = 0; r < 4; ++r) {
      int c = t + 256 * r;
      if (c < C_N) {
        float lv = lam[c], sv = s[c], rpv = rp[c], rcv = rc[c];
        float g = ys[ai[c]] - ys[bi[c]];
        float dsv = -rpv - g;
        float dlv = -(rcv + lv * dsv) / sv;
        if (dsv < 0.f) amin = fminf(amin, -sv / dsv);
        if (dlv < 0.f) amin = fminf(amin, -lv / dlv);
        lamr[r] = lv; sr[r] = sv; dsr[r] = dsv; dlr[r] = dlv;
      }
    }
    float am = bmin256(amin, red);
    float alpha = fminf(1.f, 0.99f * am);
#pragma unroll
    for (int r = 0; r < 4; ++r) {
      int c = t + 256 * r;
      if (c < C_N) {
        lamr[r] += alpha * dlr[r];
        sr[r]   += alpha * dsr[r];
        lam[c] = lamr[r]; s[c] = sr[r];
      }
    }
    zs[t] += alpha * dzs[t];
    z[t] = zs[t];
    __syncthreads();
  } else {
#pragma unroll
    for (int r = 0; r < 4; ++r) {
      int c = t + 256 * r;
      if (c < C_N) { lamr[r] = lam[c]; sr[r] = s[c]; }
    }
  }

  // ys = W * z
  if (t < 250) {
    float4 acc = make_float4(0.f, 0.f, 0.f, 0.f);
    const float4* WT4 = (const float4*)WT;
#pragma unroll 4
    for (int k = 0; k < 256; ++k) {
      float zk = zs[k];
      float4 w4 = WT4[k * 250 + t];
      acc.x += zk * w4.x; acc.y += zk * w4.y; acc.z += zk * w4.z; acc.w += zk * w4.w;
    }
    *(float4*)&ys[4 * t] = acc;
  }
  __syncthreads();

  float musum = 0.f;
#pragma unroll
  for (int r = 0; r < 4; ++r) {
    int c = t + 256 * r;
    if (c < C_N) {
      float g = ys[ai[c]] - ys[bi[c]];
      rpr[r] = g + sr[r] - h[c];
      musum += lamr[r] * sr[r];
    }
  }
  float mu = bsum256(musum, red) * (1.f / 1000.f);

  float vsum = 0.f;
#pragma unroll
  for (int r = 0; r < 4; ++r) {
    int c = t + 256 * r;
    if (c < C_N) {
      float prod = lamr[r] * sr[r];
      float rcv = prod - SIGMA_C * mu;
      rc[c] = rcv; rp[c] = rpr[r];
      wbuf[c] = lamr[r] / sr[r];
      float vv = lamr[r] + (lamr[r] * rpr[r] - rcv) / sr[r];
      vs[c] = vv; vsum += vv;
    }
  }
  float S_all = bsum256(vsum, red);  // internal barriers also publish vs[]

  float vt[10];
#pragma unroll
  for (int i = 0; i < 10; ++i) vt[i] = vs[tsh[i]];
  float S_tgt = 0.f;
#pragma unroll
  for (int i = 0; i < 10; ++i) S_tgt += vt[i];
  float S_gen = S_all - S_tgt;
  __syncthreads();  // all cross-reads of vs done before in-place scatter

#pragma unroll
  for (int r = 0; r < 4; ++r) {
    int c = t + 256 * r;
    if (c < C_N) {
      int rk = -1;
#pragma unroll
      for (int i = 0; i < 10; ++i) if (c == tsh[i]) rk = i;
      float vc = vs[c];
      float u;
      if (rk < 0)        u = vc;
      else if (rk == 0)  u = -vt[1];
      else if (rk < 9)   u = vc - vt[rk + 1];
      else               u = vc - S_gen;
      vs[c] = u;
    }
  }
  __syncthreads();

  {
    float acc = 0.f;
#pragma unroll 4
    for (int c = 0; c < C_N; ++c) acc += vs[c] * W[c * F_N + t];
    rhs[t] = -(2.f * zs[t] - 2.f * feats[b * F_N + t] + acc);
  }
}

// ---------------------------------------------------------------------------
// K_C: M64 = (double)(2I + X^T diag(w) X), lower 64x64 tiles.  grid = B*10.
__global__ __launch_bounds__(256) void k_syrk(float* wsf) {
  int blk = blockIdx.x;
  int b = blk / 10, tile = blk % 10;
  const int TI[10] = {0,1,1,2,2,2,3,3,3,3};
  const int TJ[10] = {0,0,1,0,1,2,0,1,2,3};
  int ti = TI[tile], tj = TJ[tile];
  int t = threadIdx.x;
  int tx = t & 15, ty = t >> 4;
  __shared__ __align__(16) float As[64][64];  // w-weighted (row/i side)
  __shared__ __align__(16) float Bs[64][64];  // raw (col/k side)
  const float* X  = wsf + OFF_X  + (size_t)b * 256000;
  const float* wv = wsf + OFF_WV + b * C_N;
  float acc[4][4] = {{0.f}};
  int f4 = t & 15, jr0 = t >> 4;
  for (int cc = 0; cc < C_N; cc += 64) {
    __syncthreads();
#pragma unroll
    for (int rep = 0; rep < 4; ++rep) {
      int j = jr0 + rep * 16;
      int c = cc + j;
      float wj = (c < C_N) ? wv[c] : 0.f;
      float4 v = (c < C_N) ? *(const float4*)&X[(size_t)c * F_N + ti * 64 + f4 * 4]
                           : make_float4(0.f, 0.f, 0.f, 0.f);
      float4 u;
      if (tj == ti) u = v;
      else u = (c < C_N) ? *(const float4*)&X[(size_t)c * F_N + tj * 64 + f4 * 4]
                         : make_float4(0.f, 0.f, 0.f, 0.f);
      float4 vw = make_float4(wj * v.x, wj * v.y, wj * v.z, wj * v.w);
      *(float4*)&As[j][f4 * 4] = vw;
      *(float4*)&Bs[j][f4 * 4] = u;
    }
    __syncthreads();
#pragma unroll 4
    for (int j = 0; j < 64; ++j) {
      float4 a4 = *(const float4*)&As[j][tx * 4];
      float4 b4 = *(const float4*)&Bs[j][ty * 4];
      acc[0][0] += a4.x * b4.x; acc[0][1] += a4.x * b4.y; acc[0][2] += a4.x * b4.z; acc[0][3] += a4.x * b4.w;
      acc[1][0] += a4.y * b4.x; acc[1][1] += a4.y * b4.y; acc[1][2] += a4.y * b4.z; acc[1][3] += a4.y * b4.w;
      acc[2][0] += a4.z * b4.x; acc[2][1] += a4.z * b4.y; acc[2][2] += a4.z * b4.z; acc[2][3] += a4.z * b4.w;
      acc[3][0] += a4.w * b4.x; acc[3][1] += a4.w * b4.y; acc[3][2] += a4.w * b4.z; acc[3][3] += a4.w * b4.w;
    }
  }
  double* M64 = (double*)(wsf + OFF_M64) + (size_t)b * 65536;
#pragma unroll
  for (int e = 0; e < 4; ++e) {
    int i = ti * 64 + tx * 4 + e;
    int k0 = tj * 64 + ty * 4;
#pragma unroll
    for (int q = 0; q < 4; ++q) {
      float v = acc[e][q] + ((i == k0 + q) ? 2.f : 0.f);
      M64[(size_t)i * F_N + k0 + q] = (double)v;
    }
  }
}

// ---------------------------------------------------------------------------
// K_D v2: f64 LDL^T, NB=32 (8 panels, 24 barriers vs 48), 1024 threads
// (2x trailing-tile parallelism + MLP), u-only LDS panel + on-the-fly
// L = u*invd in the trailing update, XOR column swizzle (f64 even-bank-
// stride fix).  Then unit-L solves + D-divide.  One block per batch.
#define PUX(r, j) Pu[(r) * 33 + ((j) ^ (((r) >> 2) & 7))]

__global__ __launch_bounds__(1024) void k_chol(float* wsf) {
  int b = blockIdx.x, t = threadIdx.x;
  double* M = (double*)(wsf + OFF_M64) + (size_t)b * 65536;
  __shared__ double Sm[8480];      // Db[32*33] | invd[32] | Pu[224*33]
  __shared__ double yv[256];
  __shared__ double red2[16 * 65];
  double* Db   = Sm;               // [32][33]
  double* invd = Sm + 1056;        // [32]
  double* Pu   = Sm + 1088;        // [224][33], swizzled cols (holds u = L*d)

  for (int p = 0; p < 8; ++p) {
    int p0 = p * 32, p1 = p0 + 32, nb = 256 - p1;

    // phase a: 32x32 LDL^T diag block, lanes 0..31 (wave 0), rows in regs
    if (t < 32) {
      int l = t;
      double a[32];
#pragma unroll
      for (int q = 0; q < 32; ++q) a[q] = M[(size_t)(p0 + l) * F_N + p0 + q];
#pragma unroll
      for (int j = 0; j < 32; ++j) {
        double d = __shfl(a[j], j);
        double dc = (fabs(d) < 1e-30) ? (d < 0.0 ? -1e-30 : 1e-30) : d;
        double inv = 1.0 / dc;
        if (l == j) a[j] = dc;
        else if (l > j) a[j] *= inv;
#pragma unroll
        for (int k = j + 1; k < 32; ++k) {
          double lkj = __shfl(a[j], k);   // L[k][j]
          if (l >= k) a[k] -= a[j] * (lkj * dc);
        }
      }
#pragma unroll
      for (int q = 0; q < 32; ++q) {
        M[(size_t)(p0 + l) * F_N + p0 + q] = a[q];
        Db[l * 33 + q] = a[q];
      }
      invd[l] = 1.0 / a[l];
    }
    __syncthreads();

    // phase b: panel rows below (one row/thread); keep u in LDS, L to global
    if (t < nb) {
      int r = p1 + t;
      double x[32];
#pragma unroll
      for (int q = 0; q < 32; ++q) x[q] = M[(size_t)r * F_N + p0 + q];
#pragma unroll
      for (int k = 0; k < 32; ++k) {
        double uk = x[k];
#pragma unroll
        for (int j = k + 1; j < 32; ++j) x[j] -= uk * Db[j * 33 + k];
        x[k] = uk * invd[k];
        PUX(t, k) = uk;
      }
#pragma unroll
      for (int q = 0; q < 32; ++q) M[(size_t)r * F_N + p0 + q] = x[q];
    }
    __syncthreads();

    // phase c: trailing A -= u * invd * u^T  (4x4 tiles over lower triangle)
    int nt4 = nb >> 2;
    int Ntile = nt4 * (nt4 + 1) / 2;
    for (int tt = t; tt < Ntile; tt += 1024) {
      float fsq = sqrtf((float)(8 * tt + 1));
      int ti = (int)((fsq - 1.f) * 0.5f);
      while ((ti + 1) * (ti + 2) / 2 <= tt) ++ti;
      while (ti * (ti + 1) / 2 > tt) --ti;
      int tk = tt - ti * (ti + 1) / 2;
      int ib = ti * 4, kb = tk * 4;
      double* m0 = M + (size_t)(p1 + ib) * F_N + p1 + kb;
      double a00 = m0[0],   a01 = m0[1],   a02 = m0[2],   a03 = m0[3];
      double a10 = m0[256], a11 = m0[257], a12 = m0[258], a13 = m0[259];
      double a20 = m0[512], a21 = m0[513], a22 = m0[514], a23 = m0[515];
      double a30 = m0[768], a31 = m0[769], a32 = m0[770], a33 = m0[771];
#pragma unroll
      for (int j = 0; j < 32; ++j) {
        double dj = invd[j];
        double A0 = PUX(ib + 0, j), A1 = PUX(ib + 1, j);
        double A2 = PUX(ib + 2, j), A3 = PUX(ib + 3, j);
        double B0 = PUX(kb + 0, j) * dj, B1 = PUX(kb + 1, j) * dj;
        double B2 = PUX(kb + 2, j) * dj, B3 = PUX(kb + 3, j) * dj;
        a00 -= A0 * B0; a01 -= A0 * B1; a02 -= A0 * B2; a03 -= A0 * B3;
        a10 -= A1 * B0; a11 -= A1 * B1; a12 -= A1 * B2; a13 -= A1 * B3;
        a20 -= A2 * B0; a21 -= A2 * B1; a22 -= A2 * B2; a23 -= A2 * B3;
        a30 -= A3 * B0; a31 -= A3 * B1; a32 -= A3 * B2; a33 -= A3 * B3;
      }
      m0[0]   = a00; m0[1]   = a01; m0[2]   = a02; m0[3]   = a03;
      m0[256] = a10; m0[257] = a11; m0[258] = a12; m0[259] = a13;
      m0[512] = a20; m0[513] = a21; m0[514] = a22; m0[515] = a23;
      m0[768] = a30; m0[769] = a31; m0[770] = a32; m0[771] = a33;
    }
    __syncthreads();
  }

  // ---- triangular solves (unit L), D-divide in the middle ----
  {
    const float* rhs = wsf + OFF_RHS + (size_t)b * F_N;
    if (t < 256) yv[t] = (double)rhs[t];
  }
  __syncthreads();
  double* Ls = Sm;  // [64][66] = 4224 doubles <= 8480 (Db/Pu dead)

  for (int blk = 0; blk < 4; ++blk) {
    int r0 = blk * 64;
    {
      int row = t >> 4, c4 = (t & 15) * 4;
#pragma unroll
      for (int q = 0; q < 4; ++q)
        Ls[row * 66 + c4 + q] = M[(size_t)(r0 + row) * F_N + r0 + c4 + q];
    }
    __syncthreads();
    if (t < 64) {
      int l = t;
      double acc = yv[r0 + l];
#pragma unroll
      for (int j = 0; j < 64; ++j) {
        double xj = __shfl(acc, j);
        if (l > j) acc -= Ls[l * 66 + j] * xj;
      }
      yv[r0 + l] = acc;
    }
    __syncthreads();
    int nrem = 192 - blk * 64;
    if (t < nrem) {
      int r = r0 + 64 + t;
      double a2 = 0.0;
#pragma unroll 4
      for (int j = 0; j < 64; ++j) a2 += M[(size_t)r * F_N + r0 + j] * yv[r0 + j];
      yv[r] -= a2;
    }
    __syncthreads();
  }

  if (t < 256) yv[t] = yv[t] / M[(size_t)t * F_N + t];
  __syncthreads();

  for (int blk = 3; blk >= 0; --blk) {
    int r0 = blk * 64, r1 = r0 + 64;
    if (blk < 3) {
      int i = r0 + (t & 63), g = t >> 6;   // 16 groups of 64
      double part = 0.0;
      for (int j = r1 + g; j < 256; j += 16) part += M[(size_t)j * F_N + i] * yv[j];
      red2[g * 65 + (t & 63)] = part;
      __syncthreads();
      if (t < 64) {
        double tot = 0.0;
#pragma unroll
        for (int g2 = 0; g2 < 16; ++g2) tot += red2[g2 * 65 + t];
        yv[r0 + t] -= tot;
      }
      __syncthreads();
    }
    {
      int row = t >> 4, c4 = (t & 15) * 4;
#pragma unroll
      for (int q = 0; q < 4; ++q)
        Ls[row * 66 + c4 + q] = M[(size_t)(r0 + row) * F_N + r0 + c4 + q];
    }
    __syncthreads();
    if (t < 64) {
      int l = t;
      double acc = yv[r0 + l];
#pragma unroll
      for (int j = 63; j >= 0; --j) {
        double xj = __shfl(acc, j);
        if (l < j) acc -= Ls[j * 66 + l] * xj;
      }
      yv[r0 + l] = acc;
    }
    __syncthreads();
  }

  if (t < 256) (wsf + OFF_DZ)[(size_t)b * F_N + t] = (float)yv[t];
}

// ---------------------------------------------------------------------------
// K_E: apply the 20th update and compute loss[b] = sum_k (feats - z)^2
__global__ __launch_bounds__(256) void k_final(const float* __restrict__ feats,
                                               float* wsf, float* __restrict__ out) {
  int b = blockIdx.x, t = threadIdx.x;
  __shared__ float zs[256], dzs[256];
  __shared__ __align__(16) float ys[1000];
  __shared__ float red[4];
  const float* WT = wsf + OFF_WT;
  const int* ai  = (const int*)(wsf + OFF_AI) + b * C_N;
  const int* bi  = (const int*)(wsf + OFF_BI) + b * C_N;
  const float* lam = wsf + OFF_LAM + b * C_N;
  const float* s   = wsf + OFF_S   + b * C_N;
  const float* rp  = wsf + OFF_RP  + b * C_N;
  const float* rc  = wsf + OFF_RC  + b * C_N;
  const float* z   = wsf + OFF_Z   + b * F_N;
  const float* dz  = wsf + OFF_DZ  + b * F_N;

  zs[t] = z[t];
  dzs[t] = dz[t];
  __syncthreads();
  if (t < 250) {
    float4 acc = make_float4(0.f, 0.f, 0.f, 0.f);
    const float4* WT4 = (const float4*)WT;
#pragma unroll 4
    for (int k = 0; k < 256; ++k) {
      float zk = dzs[k];
      float4 w4 = WT4[k * 250 + t];
      acc.x += zk * w4.x; acc.y += zk * w4.y; acc.z += zk * w4.z; acc.w += zk * w4.w;
    }
    *(float4*)&ys[4 * t] = acc;
  }
  __syncthreads();
  float amin = BIGV;
#pragma unroll
  for (int r = 0; r < 4; ++r) {
    int c = t + 256 * r;
    if (c < C_N) {
      float lv = lam[c], sv = s[c], rpv = rp[c], rcv = rc[c];
      float g = ys[ai[c]] - ys[bi[c]];
      float dsv = -rpv - g;
      float dlv = -(rcv + lv * dsv) / sv;
      if (dsv < 0.f) amin = fminf(amin, -sv / dsv);
      if (dlv < 0.f) amin = fminf(amin, -lv / dlv);
    }
  }
  float am = bmin256(amin, red);
  float alpha = fminf(1.f, 0.99f * am);
  float zf = zs[t] + alpha * dzs[t];
  float d = feats[b * F_N + t] - zf;
  float loss = bsum256(d * d, red);
  if (t == 0) out[b] = loss;
}

// ---------------------------------------------------------------------------
extern "C" void kernel_launch(void* const* d_in, const int* in_sizes, int n_in,
                              void* d_out, int out_size, void* d_ws, size_t ws_size,
                              hipStream_t stream) {
  (void)in_sizes; (void)n_in; (void)out_size; (void)ws_size;
  const float* feats = (const float*)d_in[1];
  const int*   tg    = (const int*)d_in[3];
  const float* W     = (const float*)d_in[4];
  const float* bias  = (const float*)d_in[5];
  const float* marg  = (const float*)d_in[6];
  float* wsf = (float*)d_ws;
  float* out = (float*)d_out;

  k_transpose<<<64, 256, 0, stream>>>(W, wsf + OFF_WT);
  k_setup<<<B_N, 256, 0, stream>>>(tg, bias, feats, marg, wsf);
  k_buildX<<<B_N * 8, 256, 0, stream>>>(W, wsf);   // once: X is iteration-invariant
  for (int it = 0; it < ITERS_N; ++it) {
    k_iter_pre<<<B_N, 256, 0, stream>>>(W, feats, tg, wsf, it > 0 ? 1 : 0);
    k_syrk<<<B_N * 10, 256, 0, stream>>>(wsf);
    k_chol<<<B_N, 1024, 0, stream>>>(wsf);
  }
  k_final<<<B_N, 256, 0, stream>>>(feats, wsf, out);
}

// Round 9
// 19739.684 us; speedup vs baseline: 1.0006x; 1.0006x over previous
//
#include <hip/hip_runtime.h>

// ---------------------------------------------------------------------------
// CVXProjLoss: batched QP interior-point projection.
// B=16, C=1000 (constraints m), F=256 (vars n), K=10, 20 IPM iters.
//
// Structure: D has <=2 nonzeros per row, so
//   G[b,c,:] = W[a_c] - W[b_c]   (a_c=b_c=0 => zero row for c == t0)
//   G z      = (W z)[a] - (W z)[b]
//   G^T v    = W^T u,  u = closed-form scatter of v
//   M        = 2I + sum_c w_c g_c g_c^T   (w applied inside SYRK; no sqrt)
// Solver: f64 LDL^T (no sqrt).
// R6: NB=16/512t = 250us steady (latency-bound).
// R8: NB=32/1024t REGRESSED to 813us: compiler capped VGPR at 64 (8 waves/EU
//     heuristic for 1024t) -> a[32]/x[32] f64 panel arrays spilled to scratch
//     (HBM traffic 7x: WRITE 4.4->41.5MB, VALUBusy 0.92->0.30).
// R9: __launch_bounds__(1024, 4) -> VGPR cap 128 (1 block/CU, which 78KB LDS
//     forces anyway) -> no spill.  Only change vs R8.
// ---------------------------------------------------------------------------

#define B_N 16
#define C_N 1000
#define F_N 256
#define ITERS_N 20
#define SIGMA_C 0.1f
#define BIGV 1e10f

// ws layout (float offsets)
static const size_t OFF_WT  = 0;                      // 256*1000
static const size_t OFF_X   = 256000;                 // 16*1000*256 (unweighted rows)
static const size_t OFF_M64 = 4352000;                // f64 16*256*256 (= 2097152 floats)
static const size_t OFF_H   = 6449152;                // 16*1000
static const size_t OFF_LAM = OFF_H   + 16000;
static const size_t OFF_S   = OFF_LAM + 16000;
static const size_t OFF_RP  = OFF_S   + 16000;
static const size_t OFF_RC  = OFF_RP  + 16000;
static const size_t OFF_WV  = OFF_RC  + 16000;        // w = lam/s
static const size_t OFF_Z   = OFF_WV  + 16000;        // 16*256
static const size_t OFF_DZ  = OFF_Z   + 4096;
static const size_t OFF_RHS = OFF_DZ  + 4096;
static const size_t OFF_AI  = OFF_RHS + 4096;         // int 16*1000
static const size_t OFF_BI  = OFF_AI  + 16000;        // int 16*1000
// end = OFF_BI + 16000 = 6,589,440 floats ~= 25.1 MiB

__device__ __forceinline__ float bsum256(float v, float* red) {
#pragma unroll
  for (int o = 32; o > 0; o >>= 1) v += __shfl_down(v, o);
  __syncthreads();
  if ((threadIdx.x & 63) == 0) red[threadIdx.x >> 6] = v;
  __syncthreads();
  return red[0] + red[1] + red[2] + red[3];
}
__device__ __forceinline__ float bmin256(float v, float* red) {
#pragma unroll
  for (int o = 32; o > 0; o >>= 1) v = fminf(v, __shfl_down(v, o));
  __syncthreads();
  if ((threadIdx.x & 63) == 0) red[threadIdx.x >> 6] = v;
  __syncthreads();
  return fminf(fminf(red[0], red[1]), fminf(red[2], red[3]));
}

// ---------------------------------------------------------------------------
// S1: WT[k][c] = W[c][k]   (64x64 LDS-tiled transpose)
__global__ __launch_bounds__(256) void k_transpose(const float* __restrict__ W,
                                                   float* __restrict__ WT) {
  __shared__ float tile[64][65];
  int tc = blockIdx.x & 15, tk = blockIdx.x >> 4;
  int c0 = tc * 64, k0 = tk * 64;
  int t = threadIdx.x;
  int jj = t & 63, r4 = t >> 6;
#pragma unroll
  for (int i = 0; i < 16; ++i) {
    int r = r4 + i * 4;
    int c = c0 + r;
    tile[r][jj] = (c < C_N) ? W[c * F_N + k0 + jj] : 0.f;
  }
  __syncthreads();
#pragma unroll
  for (int i = 0; i < 16; ++i) {
    int kr = r4 + i * 4;
    int cc = c0 + jj;
    if (cc < C_N) WT[(k0 + kr) * C_N + cc] = tile[jj][kr];
  }
}

// ---------------------------------------------------------------------------
// S2: build a_idx, b_idx, h; init lam=s=1, z=feats_pred
__global__ __launch_bounds__(256) void k_setup(const int* __restrict__ tg,
                                               const float* __restrict__ bias,
                                               const float* __restrict__ feats,
                                               const float* __restrict__ marg,
                                               float* wsf) {
  int b = blockIdx.x, t = threadIdx.x;
  __shared__ int tsh[10];
  if (t < 10) tsh[t] = tg[b * 10 + t];
  __syncthreads();
  float m = marg[0];
  int t9 = tsh[9];
  float bias_t9 = bias[t9];
  int*   ai  = (int*)(wsf + OFF_AI) + b * C_N;
  int*   bi  = (int*)(wsf + OFF_BI) + b * C_N;
  float* h   = wsf + OFF_H   + b * C_N;
  float* lam = wsf + OFF_LAM + b * C_N;
  float* s   = wsf + OFF_S   + b * C_N;
#pragma unroll
  for (int r = 0; r < 4; ++r) {
    int c = t + 256 * r;
    if (c < C_N) {
      int rk = -1;
#pragma unroll
      for (int i = 0; i < 10; ++i) if (c == tsh[i]) rk = i;
      int av, bv; float hv;
      if (rk < 0)       { av = c;        bv = t9;         hv = bias_t9 - bias[c] - m; }
      else if (rk == 0) { av = 0;        bv = 0;          hv = 0.f; }
      else              { av = tsh[rk];  bv = tsh[rk-1];  hv = bias[tsh[rk-1]] - bias[tsh[rk]] - m; }
      ai[c] = av; bi[c] = bv; h[c] = hv; lam[c] = 1.f; s[c] = 1.f;
    }
  }
  (wsf + OFF_Z)[b * F_N + t] = feats[b * F_N + t];
}

// ---------------------------------------------------------------------------
// K_B: X[b][c][k] = W[a_c][k] - W[b_c][k]  (UNWEIGHTED; runs ONCE).
__global__ __launch_bounds__(256) void k_buildX(const float* __restrict__ W,
                                                float* wsf) {
  int bb = blockIdx.x >> 3, part = blockIdx.x & 7;
  int t = threadIdx.x;
  __shared__ int aL[125], bL[125];
  int c0 = part * 125;
  const int* ai = (const int*)(wsf + OFF_AI) + bb * C_N;
  const int* bi = (const int*)(wsf + OFF_BI) + bb * C_N;
  if (t < 125) { aL[t] = ai[c0 + t]; bL[t] = bi[c0 + t]; }
  __syncthreads();
  float* X = wsf + OFF_X + (size_t)bb * 256000 + (size_t)c0 * F_N;
  for (int i = 0; i < 125; ++i) {
    float wa = W[aL[i] * F_N + t];
    float wb = W[bL[i] * F_N + t];
    X[i * F_N + t] = wa - wb;
  }
}

// ---------------------------------------------------------------------------
// K_A: apply previous step's update (if any), then residuals, w, scatter u,
// rhs = -(2z + p + W^T u).  One block per batch, 256 threads.
__global__ __launch_bounds__(256) void k_iter_pre(const float* __restrict__ W,
                                                  const float* __restrict__ feats,
                                                  const int* __restrict__ tg,
                                                  float* wsf, int do_update) {
  int b = blockIdx.x, t = threadIdx.x;
  __shared__ float zs[256], dzs[256];
  __shared__ __align__(16) float ys[1000];
  __shared__ float vs[1000];
  __shared__ float red[4];
  __shared__ int tsh[10];

  const float* WT = wsf + OFF_WT;
  const int* ai  = (const int*)(wsf + OFF_AI) + b * C_N;
  const int* bi  = (const int*)(wsf + OFF_BI) + b * C_N;
  float* h    = wsf + OFF_H   + b * C_N;
  float* lam  = wsf + OFF_LAM + b * C_N;
  float* s    = wsf + OFF_S   + b * C_N;
  float* rp   = wsf + OFF_RP  + b * C_N;
  float* rc   = wsf + OFF_RC  + b * C_N;
  float* wbuf = wsf + OFF_WV  + b * C_N;
  float* z    = wsf + OFF_Z   + b * F_N;
  float* dz   = wsf + OFF_DZ  + b * F_N;
  float* rhs  = wsf + OFF_RHS + b * F_N;

  if (t < 10) tsh[t] = tg[b * 10 + t];
  zs[t] = z[t];
  if (do_update) dzs[t] = dz[t];
  __syncthreads();

  float lamr[4], sr[4], rpr[4];
  if (do_update) {
    if (t < 250) {
      float4 acc = make_float4(0.f, 0.f, 0.f, 0.f);
      const float4* WT4 = (const float4*)WT;
#pragma unroll 4
      for (int k = 0; k < 256; ++k) {
        float zk = dzs[k];
        float4 w4 = WT4[k * 250 + t];
        acc.x += zk * w4.x; acc.y += zk * w4.y; acc.z += zk * w4.z; acc.w += zk * w4.w;
      }
      *(float4*)&ys[4 * t] = acc;
    }
    __syncthreads();
    float amin = BIGV;
    float dsr[4], dlr[4];
#pragma unroll
    for (int r = 0; r < 4; ++r) {
      int c = t + 256 * r;
      if (c < C_N) {
        float lv = lam[c], sv = s[c], rpv = rp[c], rcv = rc[c];
        float g = ys[ai[c]] - ys[bi[c]];
        float dsv = -rpv - g;
        float dlv = -(rcv + lv * dsv) / sv;
        if (dsv < 0.f) amin = fminf(amin, -sv / dsv);
        if (dlv < 0.f) amin = fminf(amin, -lv / dlv);
        lamr[r] = lv; sr[r] = sv; dsr[r] = dsv; dlr[r] = dlv;
      }
    }
    float am = bmin256(amin, red);
    float alpha = fminf(1.f, 0.99f * am);
#pragma unroll
    for (int r = 0; r < 4; ++r) {
      int c = t + 256 * r;
      if (c < C_N) {
        lamr[r] += alpha * dlr[r];
        sr[r]   += alpha * dsr[r];
        lam[c] = lamr[r]; s[c] = sr[r];
      }
    }
    zs[t] += alpha * dzs[t];
    z[t] = zs[t];
    __syncthreads();
  } else {
#pragma unroll
    for (int r = 0; r < 4; ++r) {
      int c = t + 256 * r;
      if (c < C_N) { lamr[r] = lam[c]; sr[r] = s[c]; }
    }
  }

  // ys = W * z
  if (t < 250) {
    float4 acc = make_float4(0.f, 0.f, 0.f, 0.f);
    const float4* WT4 = (const float4*)WT;
#pragma unroll 4
    for (int k = 0; k < 256; ++k) {
      float zk = zs[k];
      float4 w4 = WT4[k * 250 + t];
      acc.x += zk * w4.x; acc.y += zk * w4.y; acc.z += zk * w4.z; acc.w += zk * w4.w;
    }
    *(float4*)&ys[4 * t] = acc;
  }
  __syncthreads();

  float musum = 0.f;
#pragma unroll
  for (int r = 0; r < 4; ++r) {
    int c = t + 256 * r;
    if (c < C_N) {
      float g = ys[ai[c]] - ys[bi[c]];
      rpr[r] = g + sr[r] - h[c];
      musum += lamr[r] * sr[r];
    }
  }
  float mu = bsum256(musum, red) * (1.f / 1000.f);

  float vsum = 0.f;
#pragma unroll
  for (int r = 0; r < 4; ++r) {
    int c = t + 256 * r;
    if (c < C_N) {
      float prod = lamr[r] * sr[r];
      float rcv = prod - SIGMA_C * mu;
      rc[c] = rcv; rp[c] = rpr[r];
      wbuf[c] = lamr[r] / sr[r];
      float vv = lamr[r] + (lamr[r] * rpr[r] - rcv) / sr[r];
      vs[c] = vv; vsum += vv;
    }
  }
  float S_all = bsum256(vsum, red);  // internal barriers also publish vs[]

  float vt[10];
#pragma unroll
  for (int i = 0; i < 10; ++i) vt[i] = vs[tsh[i]];
  float S_tgt = 0.f;
#pragma unroll
  for (int i = 0; i < 10; ++i) S_tgt += vt[i];
  float S_gen = S_all - S_tgt;
  __syncthreads();  // all cross-reads of vs done before in-place scatter

#pragma unroll
  for (int r = 0; r < 4; ++r) {
    int c = t + 256 * r;
    if (c < C_N) {
      int rk = -1;
#pragma unroll
      for (int i = 0; i < 10; ++i) if (c == tsh[i]) rk = i;
      float vc = vs[c];
      float u;
      if (rk < 0)        u = vc;
      else if (rk == 0)  u = -vt[1];
      else if (rk < 9)   u = vc - vt[rk + 1];
      else               u = vc - S_gen;
      vs[c] = u;
    }
  }
  __syncthreads();

  {
    float acc = 0.f;
#pragma unroll 4
    for (int c = 0; c < C_N; ++c) acc += vs[c] * W[c * F_N + t];
    rhs[t] = -(2.f * zs[t] - 2.f * feats[b * F_N + t] + acc);
  }
}

// ---------------------------------------------------------------------------
// K_C: M64 = (double)(2I + X^T diag(w) X), lower 64x64 tiles.  grid = B*10.
__global__ __launch_bounds__(256) void k_syrk(float* wsf) {
  int blk = blockIdx.x;
  int b = blk / 10, tile = blk % 10;
  const int TI[10] = {0,1,1,2,2,2,3,3,3,3};
  const int TJ[10] = {0,0,1,0,1,2,0,1,2,3};
  int ti = TI[tile], tj = TJ[tile];
  int t = threadIdx.x;
  int tx = t & 15, ty = t >> 4;
  __shared__ __align__(16) float As[64][64];  // w-weighted (row/i side)
  __shared__ __align__(16) float Bs[64][64];  // raw (col/k side)
  const float* X  = wsf + OFF_X  + (size_t)b * 256000;
  const float* wv = wsf + OFF_WV + b * C_N;
  float acc[4][4] = {{0.f}};
  int f4 = t & 15, jr0 = t >> 4;
  for (int cc = 0; cc < C_N; cc += 64) {
    __syncthreads();
#pragma unroll
    for (int rep = 0; rep < 4; ++rep) {
      int j = jr0 + rep * 16;
      int c = cc + j;
      float wj = (c < C_N) ? wv[c] : 0.f;
      float4 v = (c < C_N) ? *(const float4*)&X[(size_t)c * F_N + ti * 64 + f4 * 4]
                           : make_float4(0.f, 0.f, 0.f, 0.f);
      float4 u;
      if (tj == ti) u = v;
      else u = (c < C_N) ? *(const float4*)&X[(size_t)c * F_N + tj * 64 + f4 * 4]
                         : make_float4(0.f, 0.f, 0.f, 0.f);
      float4 vw = make_float4(wj * v.x, wj * v.y, wj * v.z, wj * v.w);
      *(float4*)&As[j][f4 * 4] = vw;
      *(float4*)&Bs[j][f4 * 4] = u;
    }
    __syncthreads();
#pragma unroll 4
    for (int j = 0; j < 64; ++j) {
      float4 a4 = *(const float4*)&As[j][tx * 4];
      float4 b4 = *(const float4*)&Bs[j][ty * 4];
      acc[0][0] += a4.x * b4.x; acc[0][1] += a4.x * b4.y; acc[0][2] += a4.x * b4.z; acc[0][3] += a4.x * b4.w;
      acc[1][0] += a4.y * b4.x; acc[1][1] += a4.y * b4.y; acc[1][2] += a4.y * b4.z; acc[1][3] += a4.y * b4.w;
      acc[2][0] += a4.z * b4.x; acc[2][1] += a4.z * b4.y; acc[2][2] += a4.z * b4.z; acc[2][3] += a4.z * b4.w;
      acc[3][0] += a4.w * b4.x; acc[3][1] += a4.w * b4.y; acc[3][2] += a4.w * b4.z; acc[3][3] += a4.w * b4.w;
    }
  }
  double* M64 = (double*)(wsf + OFF_M64) + (size_t)b * 65536;
#pragma unroll
  for (int e = 0; e < 4; ++e) {
    int i = ti * 64 + tx * 4 + e;
    int k0 = tj * 64 + ty * 4;
#pragma unroll
    for (int q = 0; q < 4; ++q) {
      float v = acc[e][q] + ((i == k0 + q) ? 2.f : 0.f);
      M64[(size_t)i * F_N + k0 + q] = (double)v;
    }
  }
}

// ---------------------------------------------------------------------------
// K_D v3: f64 LDL^T, NB=32, 1024 threads, u-only LDS panel + XOR swizzle.
// __launch_bounds__(1024, 4): 4 waves/EU -> VGPR cap 128 (vs default 64 that
// spilled a[32]/x[32] to scratch in R8).  LDS 78KB forces 1 block/CU anyway.
#define PUX(r, j) Pu[(r) * 33 + ((j) ^ (((r) >> 2) & 7))]

__global__ __launch_bounds__(1024, 4) void k_chol(float* wsf) {
  int b = blockIdx.x, t = threadIdx.x;
  double* M = (double*)(wsf + OFF_M64) + (size_t)b * 65536;
  __shared__ double Sm[8480];      // Db[32*33] | invd[32] | Pu[224*33]
  __shared__ double yv[256];
  __shared__ double red2[16 * 65];
  double* Db   = Sm;               // [32][33]
  double* invd = Sm + 1056;        // [32]
  double* Pu   = Sm + 1088;        // [224][33], swizzled cols (holds u = L*d)

  for (int p = 0; p < 8; ++p) {
    int p0 = p * 32, p1 = p0 + 32, nb = 256 - p1;

    // phase a: 32x32 LDL^T diag block, lanes 0..31 (wave 0), rows in regs
    if (t < 32) {
      int l = t;
      double a[32];
#pragma unroll
      for (int q = 0; q < 32; ++q) a[q] = M[(size_t)(p0 + l) * F_N + p0 + q];
#pragma unroll
      for (int j = 0; j < 32; ++j) {
        double d = __shfl(a[j], j);
        double dc = (fabs(d) < 1e-30) ? (d < 0.0 ? -1e-30 : 1e-30) : d;
        double inv = 1.0 / dc;
        if (l == j) a[j] = dc;
        else if (l > j) a[j] *= inv;
#pragma unroll
        for (int k = j + 1; k < 32; ++k) {
          double lkj = __shfl(a[j], k);   // L[k][j]
          if (l >= k) a[k] -= a[j] * (lkj * dc);
        }
      }
#pragma unroll
      for (int q = 0; q < 32; ++q) {
        M[(size_t)(p0 + l) * F_N + p0 + q] = a[q];
        Db[l * 33 + q] = a[q];
      }
      invd[l] = 1.0 / a[l];
    }
    __syncthreads();

    // phase b: panel rows below (one row/thread); keep u in LDS, L to global
    if (t < nb) {
      int r = p1 + t;
      double x[32];
#pragma unroll
      for (int q = 0; q < 32; ++q) x[q] = M[(size_t)r * F_N + p0 + q];
#pragma unroll
      for (int k = 0; k < 32; ++k) {
        double uk = x[k];
#pragma unroll
        for (int j = k + 1; j < 32; ++j) x[j] -= uk * Db[j * 33 + k];
        x[k] = uk * invd[k];
        PUX(t, k) = uk;
      }
#pragma unroll
      for (int q = 0; q < 32; ++q) M[(size_t)r * F_N + p0 + q] = x[q];
    }
    __syncthreads();

    // phase c: trailing A -= u * invd * u^T  (4x4 tiles over lower triangle)
    int nt4 = nb >> 2;
    int Ntile = nt4 * (nt4 + 1) / 2;
    for (int tt = t; tt < Ntile; tt += 1024) {
      float fsq = sqrtf((float)(8 * tt + 1));
      int ti = (int)((fsq - 1.f) * 0.5f);
      while ((ti + 1) * (ti + 2) / 2 <= tt) ++ti;
      while (ti * (ti + 1) / 2 > tt) --ti;
      int tk = tt - ti * (ti + 1) / 2;
      int ib = ti * 4, kb = tk * 4;
      double* m0 = M + (size_t)(p1 + ib) * F_N + p1 + kb;
      double a00 = m0[0],   a01 = m0[1],   a02 = m0[2],   a03 = m0[3];
      double a10 = m0[256], a11 = m0[257], a12 = m0[258], a13 = m0[259];
      double a20 = m0[512], a21 = m0[513], a22 = m0[514], a23 = m0[515];
      double a30 = m0[768], a31 = m0[769], a32 = m0[770], a33 = m0[771];
#pragma unroll
      for (int j = 0; j < 32; ++j) {
        double dj = invd[j];
        double A0 = PUX(ib + 0, j), A1 = PUX(ib + 1, j);
        double A2 = PUX(ib + 2, j), A3 = PUX(ib + 3, j);
        double B0 = PUX(kb + 0, j) * dj, B1 = PUX(kb + 1, j) * dj;
        double B2 = PUX(kb + 2, j) * dj, B3 = PUX(kb + 3, j) * dj;
        a00 -= A0 * B0; a01 -= A0 * B1; a02 -= A0 * B2; a03 -= A0 * B3;
        a10 -= A1 * B0; a11 -= A1 * B1; a12 -= A1 * B2; a13 -= A1 * B3;
        a20 -= A2 * B0; a21 -= A2 * B1; a22 -= A2 * B2; a23 -= A2 * B3;
        a30 -= A3 * B0; a31 -= A3 * B1; a32 -= A3 * B2; a33 -= A3 * B3;
      }
      m0[0]   = a00; m0[1]   = a01; m0[2]   = a02; m0[3]   = a03;
      m0[256] = a10; m0[257] = a11; m0[258] = a12; m0[259] = a13;
      m0[512] = a20; m0[513] = a21; m0[514] = a22; m0[515] = a23;
      m0[768] = a30; m0[769] = a31; m0[770] = a32; m0[771] = a33;
    }
    __syncthreads();
  }

  // ---- triangular solves (unit L), D-divide in the middle ----
  {
    const float* rhs = wsf + OFF_RHS + (size_t)b * F_N;
    if (t < 256) yv[t] = (double)rhs[t];
  }
  __syncthreads();
  double* Ls = Sm;  // [64][66] = 4224 doubles <= 8480 (Db/Pu dead)

  for (int blk = 0; blk < 4; ++blk) {
    int r0 = blk * 64;
    {
      int row = t >> 4, c4 = (t & 15) * 4;
#pragma unroll
      for (int q = 0; q < 4; ++q)
        Ls[row * 66 + c4 + q] = M[(size_t)(r0 + row) * F_N + r0 + c4 + q];
    }
    __syncthreads();
    if (t < 64) {
      int l = t;
      double acc = yv[r0 + l];
#pragma unroll
      for (int j = 0; j < 64; ++j) {
        double xj = __shfl(acc, j);
        if (l > j) acc -= Ls[l * 66 + j] * xj;
      }
      yv[r0 + l] = acc;
    }
    __syncthreads();
    int nrem = 192 - blk * 64;
    if (t < nrem) {
      int r = r0 + 64 + t;
      double a2 = 0.0;
#pragma unroll 4
      for (int j = 0; j < 64; ++j) a2 += M[(size_t)r * F_N + r0 + j] * yv[r0 + j];
      yv[r] -= a2;
    }
    __syncthreads();
  }

  if (t < 256) yv[t] = yv[t] / M[(size_t)t * F_N + t];
  __syncthreads();

  for (int blk = 3; blk >= 0; --blk) {
    int r0 = blk * 64, r1 = r0 + 64;
    if (blk < 3) {
      int i = r0 + (t & 63), g = t >> 6;   // 16 groups of 64
      double part = 0.0;
      for (int j = r1 + g; j < 256; j += 16) part += M[(size_t)j * F_N + i] * yv[j];
      red2[g * 65 + (t & 63)] = part;
      __syncthreads();
      if (t < 64) {
        double tot = 0.0;
#pragma unroll
        for (int g2 = 0; g2 < 16; ++g2) tot += red2[g2 * 65 + t];
        yv[r0 + t] -= tot;
      }
      __syncthreads();
    }
    {
      int row = t >> 4, c4 = (t & 15) * 4;
#pragma unroll
      for (int q = 0; q < 4; ++q)
        Ls[row * 66 + c4 + q] = M[(size_t)(r0 + row) * F_N + r0 + c4 + q];
    }
    __syncthreads();
    if (t < 64) {
      int l = t;
      double acc = yv[r0 + l];
#pragma unroll
      for (int j = 63; j >= 0; --j) {
        double xj = __shfl(acc, j);
        if (l < j) acc -= Ls[j * 66 + l] * xj;
      }
      yv[r0 + l] = acc;
    }
    __syncthreads();
  }

  if (t < 256) (wsf + OFF_DZ)[(size_t)b * F_N + t] = (float)yv[t];
}

// ---------------------------------------------------------------------------
// K_E: apply the 20th update and compute loss[b] = sum_k (feats - z)^2
__global__ __launch_bounds__(256) void k_final(const float* __restrict__ feats,
                                               float* wsf, float* __restrict__ out) {
  int b = blockIdx.x, t = threadIdx.x;
  __shared__ float zs[256], dzs[256];
  __shared__ __align__(16) float ys[1000];
  __shared__ float red[4];
  const float* WT = wsf + OFF_WT;
  const int* ai  = (const int*)(wsf + OFF_AI) + b * C_N;
  const int* bi  = (const int*)(wsf + OFF_BI) + b * C_N;
  const float* lam = wsf + OFF_LAM + b * C_N;
  const float* s   = wsf + OFF_S   + b * C_N;
  const float* rp  = wsf + OFF_RP  + b * C_N;
  const float* rc  = wsf + OFF_RC  + b * C_N;
  const float* z   = wsf + OFF_Z   + b * F_N;
  const float* dz  = wsf + OFF_DZ  + b * F_N;

  zs[t] = z[t];
  dzs[t] = dz[t];
  __syncthreads();
  if (t < 250) {
    float4 acc = make_float4(0.f, 0.f, 0.f, 0.f);
    const float4* WT4 = (const float4*)WT;
#pragma unroll 4
    for (int k = 0; k < 256; ++k) {
      float zk = dzs[k];
      float4 w4 = WT4[k * 250 + t];
      acc.x += zk * w4.x; acc.y += zk * w4.y; acc.z += zk * w4.z; acc.w += zk * w4.w;
    }
    *(float4*)&ys[4 * t] = acc;
  }
  __syncthreads();
  float amin = BIGV;
#pragma unroll
  for (int r = 0; r < 4; ++r) {
    int c = t + 256 * r;
    if (c < C_N) {
      float lv = lam[c], sv = s[c], rpv = rp[c], rcv = rc[c];
      float g = ys[ai[c]] - ys[bi[c]];
      float dsv = -rpv - g;
      float dlv = -(rcv + lv * dsv) / sv;
      if (dsv < 0.f) amin = fminf(amin, -sv / dsv);
      if (dlv < 0.f) amin = fminf(amin, -lv / dlv);
    }
  }
  float am = bmin256(amin, red);
  float alpha = fminf(1.f, 0.99f * am);
  float zf = zs[t] + alpha * dzs[t];
  float d = feats[b * F_N + t] - zf;
  float loss = bsum256(d * d, red);
  if (t == 0) out[b] = loss;
}

// ---------------------------------------------------------------------------
extern "C" void kernel_launch(void* const* d_in, const int* in_sizes, int n_in,
                              void* d_out, int out_size, void* d_ws, size_t ws_size,
                              hipStream_t stream) {
  (void)in_sizes; (void)n_in; (void)out_size; (void)ws_size;
  const float* feats = (const float*)d_in[1];
  const int*   tg    = (const int*)d_in[3];
  const float* W     = (const float*)d_in[4];
  const float* bias  = (const float*)d_in[5];
  const float* marg  = (const float*)d_in[6];
  float* wsf = (float*)d_ws;
  float* out = (float*)d_out;

  k_transpose<<<64, 256, 0, stream>>>(W, wsf + OFF_WT);
  k_setup<<<B_N, 256, 0, stream>>>(tg, bias, feats, marg, wsf);
  k_buildX<<<B_N * 8, 256, 0, stream>>>(W, wsf);   // once: X is iteration-invariant
  for (int it = 0; it < ITERS_N; ++it) {
    k_iter_pre<<<B_N, 256, 0, stream>>>(W, feats, tg, wsf, it > 0 ? 1 : 0);
    k_syrk<<<B_N * 10, 256, 0, stream>>>(wsf);
    k_chol<<<B_N, 1024, 0, stream>>>(wsf);
  }
  k_final<<<B_N, 256, 0, stream>>>(feats, wsf, out);
}

// Round 10
// 8465.916 us; speedup vs baseline: 2.3330x; 2.3317x over previous
//
#include <hip/hip_runtime.h>

// ---------------------------------------------------------------------------
// CVXProjLoss: batched QP interior-point projection.
// B=16, C=1000 (constraints m), F=256 (vars n), K=10, 20 IPM iters.
//
// Structure: D has <=2 nonzeros per row, so
//   G[b,c,:] = W[a_c] - W[b_c]   (a_c=b_c=0 => zero row for c == t0)
//   G z      = (W z)[a] - (W z)[b]
//   G^T v    = W^T u,  u = closed-form scatter of v
//   M        = 2I + sum_c w_c g_c g_c^T   (w applied inside SYRK; no sqrt)
// Solver: f64 LDL^T (no sqrt).
// R6:  NB=16/512t, VGPR 88 -> 250us steady (latency-bound, no spill).
// R8:  NB=32/1024t -> 813us: 64-VGPR cap for 1024t spilled a[32]/x[32]
//      (WRITE 4.4->41.5MB scratch traffic).
// R9:  __launch_bounds__(1024,4) IGNORED by allocator (VGPR still 64).
// R10: NB=16 panel algebra (a[16]/x[16] = 32 VGPR, fits under the 64 cap)
//      + 1024 threads (phase-c sweeps 29->19, waves/SIMD 2->4).
// ---------------------------------------------------------------------------

#define B_N 16
#define C_N 1000
#define F_N 256
#define ITERS_N 20
#define SIGMA_C 0.1f
#define BIGV 1e10f

// ws layout (float offsets)
static const size_t OFF_WT  = 0;                      // 256*1000
static const size_t OFF_X   = 256000;                 // 16*1000*256 (unweighted rows)
static const size_t OFF_M64 = 4352000;                // f64 16*256*256 (= 2097152 floats)
static const size_t OFF_H   = 6449152;                // 16*1000
static const size_t OFF_LAM = OFF_H   + 16000;
static const size_t OFF_S   = OFF_LAM + 16000;
static const size_t OFF_RP  = OFF_S   + 16000;
static const size_t OFF_RC  = OFF_RP  + 16000;
static const size_t OFF_WV  = OFF_RC  + 16000;        // w = lam/s
static const size_t OFF_Z   = OFF_WV  + 16000;        // 16*256
static const size_t OFF_DZ  = OFF_Z   + 4096;
static const size_t OFF_RHS = OFF_DZ  + 4096;
static const size_t OFF_AI  = OFF_RHS + 4096;         // int 16*1000
static const size_t OFF_BI  = OFF_AI  + 16000;        // int 16*1000
// end = OFF_BI + 16000 = 6,589,440 floats ~= 25.1 MiB

__device__ __forceinline__ float bsum256(float v, float* red) {
#pragma unroll
  for (int o = 32; o > 0; o >>= 1) v += __shfl_down(v, o);
  __syncthreads();
  if ((threadIdx.x & 63) == 0) red[threadIdx.x >> 6] = v;
  __syncthreads();
  return red[0] + red[1] + red[2] + red[3];
}
__device__ __forceinline__ float bmin256(float v, float* red) {
#pragma unroll
  for (int o = 32; o > 0; o >>= 1) v = fminf(v, __shfl_down(v, o));
  __syncthreads();
  if ((threadIdx.x & 63) == 0) red[threadIdx.x >> 6] = v;
  __syncthreads();
  return fminf(fminf(red[0], red[1]), fminf(red[2], red[3]));
}

// ---------------------------------------------------------------------------
// S1: WT[k][c] = W[c][k]   (64x64 LDS-tiled transpose)
__global__ __launch_bounds__(256) void k_transpose(const float* __restrict__ W,
                                                   float* __restrict__ WT) {
  __shared__ float tile[64][65];
  int tc = blockIdx.x & 15, tk = blockIdx.x >> 4;
  int c0 = tc * 64, k0 = tk * 64;
  int t = threadIdx.x;
  int jj = t & 63, r4 = t >> 6;
#pragma unroll
  for (int i = 0; i < 16; ++i) {
    int r = r4 + i * 4;
    int c = c0 + r;
    tile[r][jj] = (c < C_N) ? W[c * F_N + k0 + jj] : 0.f;
  }
  __syncthreads();
#pragma unroll
  for (int i = 0; i < 16; ++i) {
    int kr = r4 + i * 4;
    int cc = c0 + jj;
    if (cc < C_N) WT[(k0 + kr) * C_N + cc] = tile[jj][kr];
  }
}

// ---------------------------------------------------------------------------
// S2: build a_idx, b_idx, h; init lam=s=1, z=feats_pred
__global__ __launch_bounds__(256) void k_setup(const int* __restrict__ tg,
                                               const float* __restrict__ bias,
                                               const float* __restrict__ feats,
                                               const float* __restrict__ marg,
                                               float* wsf) {
  int b = blockIdx.x, t = threadIdx.x;
  __shared__ int tsh[10];
  if (t < 10) tsh[t] = tg[b * 10 + t];
  __syncthreads();
  float m = marg[0];
  int t9 = tsh[9];
  float bias_t9 = bias[t9];
  int*   ai  = (int*)(wsf + OFF_AI) + b * C_N;
  int*   bi  = (int*)(wsf + OFF_BI) + b * C_N;
  float* h   = wsf + OFF_H   + b * C_N;
  float* lam = wsf + OFF_LAM + b * C_N;
  float* s   = wsf + OFF_S   + b * C_N;
#pragma unroll
  for (int r = 0; r < 4; ++r) {
    int c = t + 256 * r;
    if (c < C_N) {
      int rk = -1;
#pragma unroll
      for (int i = 0; i < 10; ++i) if (c == tsh[i]) rk = i;
      int av, bv; float hv;
      if (rk < 0)       { av = c;        bv = t9;         hv = bias_t9 - bias[c] - m; }
      else if (rk == 0) { av = 0;        bv = 0;          hv = 0.f; }
      else              { av = tsh[rk];  bv = tsh[rk-1];  hv = bias[tsh[rk-1]] - bias[tsh[rk]] - m; }
      ai[c] = av; bi[c] = bv; h[c] = hv; lam[c] = 1.f; s[c] = 1.f;
    }
  }
  (wsf + OFF_Z)[b * F_N + t] = feats[b * F_N + t];
}

// ---------------------------------------------------------------------------
// K_B: X[b][c][k] = W[a_c][k] - W[b_c][k]  (UNWEIGHTED; runs ONCE).
__global__ __launch_bounds__(256) void k_buildX(const float* __restrict__ W,
                                                float* wsf) {
  int bb = blockIdx.x >> 3, part = blockIdx.x & 7;
  int t = threadIdx.x;
  __shared__ int aL[125], bL[125];
  int c0 = part * 125;
  const int* ai = (const int*)(wsf + OFF_AI) + bb * C_N;
  const int* bi = (const int*)(wsf + OFF_BI) + bb * C_N;
  if (t < 125) { aL[t] = ai[c0 + t]; bL[t] = bi[c0 + t]; }
  __syncthreads();
  float* X = wsf + OFF_X + (size_t)bb * 256000 + (size_t)c0 * F_N;
  for (int i = 0; i < 125; ++i) {
    float wa = W[aL[i] * F_N + t];
    float wb = W[bL[i] * F_N + t];
    X[i * F_N + t] = wa - wb;
  }
}

// ---------------------------------------------------------------------------
// K_A: apply previous step's update (if any), then residuals, w, scatter u,
// rhs = -(2z + p + W^T u).  One block per batch, 256 threads.
__global__ __launch_bounds__(256) void k_iter_pre(const float* __restrict__ W,
                                                  const float* __restrict__ feats,
                                                  const int* __restrict__ tg,
                                                  float* wsf, int do_update) {
  int b = blockIdx.x, t = threadIdx.x;
  __shared__ float zs[256], dzs[256];
  __shared__ __align__(16) float ys[1000];
  __shared__ float vs[1000];
  __shared__ float red[4];
  __shared__ int tsh[10];

  const float* WT = wsf + OFF_WT;
  const int* ai  = (const int*)(wsf + OFF_AI) + b * C_N;
  const int* bi  = (const int*)(wsf + OFF_BI) + b * C_N;
  float* h    = wsf + OFF_H   + b * C_N;
  float* lam  = wsf + OFF_LAM + b * C_N;
  float* s    = wsf + OFF_S   + b * C_N;
  float* rp   = wsf + OFF_RP  + b * C_N;
  float* rc   = wsf + OFF_RC  + b * C_N;
  float* wbuf = wsf + OFF_WV  + b * C_N;
  float* z    = wsf + OFF_Z   + b * F_N;
  float* dz   = wsf + OFF_DZ  + b * F_N;
  float* rhs  = wsf + OFF_RHS + b * F_N;

  if (t < 10) tsh[t] = tg[b * 10 + t];
  zs[t] = z[t];
  if (do_update) dzs[t] = dz[t];
  __syncthreads();

  float lamr[4], sr[4], rpr[4];
  if (do_update) {
    if (t < 250) {
      float4 acc = make_float4(0.f, 0.f, 0.f, 0.f);
      const float4* WT4 = (const float4*)WT;
#pragma unroll 4
      for (int k = 0; k < 256; ++k) {
        float zk = dzs[k];
        float4 w4 = WT4[k * 250 + t];
        acc.x += zk * w4.x; acc.y += zk * w4.y; acc.z += zk * w4.z; acc.w += zk * w4.w;
      }
      *(float4*)&ys[4 * t] = acc;
    }
    __syncthreads();
    float amin = BIGV;
    float dsr[4], dlr[4];
#pragma unroll
    for (int r = 0; r < 4; ++r) {
      int c = t + 256 * r;
      if (c < C_N) {
        float lv = lam[c], sv = s[c], rpv = rp[c], rcv = rc[c];
        float g = ys[ai[c]] - ys[bi[c]];
        float dsv = -rpv - g;
        float dlv = -(rcv + lv * dsv) / sv;
        if (dsv < 0.f) amin = fminf(amin, -sv / dsv);
        if (dlv < 0.f) amin = fminf(amin, -lv / dlv);
        lamr[r] = lv; sr[r] = sv; dsr[r] = dsv; dlr[r] = dlv;
      }
    }
    float am = bmin256(amin, red);
    float alpha = fminf(1.f, 0.99f * am);
#pragma unroll
    for (int r = 0; r < 4; ++r) {
      int c = t + 256 * r;
      if (c < C_N) {
        lamr[r] += alpha * dlr[r];
        sr[r]   += alpha * dsr[r];
        lam[c] = lamr[r]; s[c] = sr[r];
      }
    }
    zs[t] += alpha * dzs[t];
    z[t] = zs[t];
    __syncthreads();
  } else {
#pragma unroll
    for (int r = 0; r < 4; ++r) {
      int c = t + 256 * r;
      if (c < C_N) { lamr[r] = lam[c]; sr[r] = s[c]; }
    }
  }

  // ys = W * z
  if (t < 250) {
    float4 acc = make_float4(0.f, 0.f, 0.f, 0.f);
    const float4* WT4 = (const float4*)WT;
#pragma unroll 4
    for (int k = 0; k < 256; ++k) {
      float zk = zs[k];
      float4 w4 = WT4[k * 250 + t];
      acc.x += zk * w4.x; acc.y += zk * w4.y; acc.z += zk * w4.z; acc.w += zk * w4.w;
    }
    *(float4*)&ys[4 * t] = acc;
  }
  __syncthreads();

  float musum = 0.f;
#pragma unroll
  for (int r = 0; r < 4; ++r) {
    int c = t + 256 * r;
    if (c < C_N) {
      float g = ys[ai[c]] - ys[bi[c]];
      rpr[r] = g + sr[r] - h[c];
      musum += lamr[r] * sr[r];
    }
  }
  float mu = bsum256(musum, red) * (1.f / 1000.f);

  float vsum = 0.f;
#pragma unroll
  for (int r = 0; r < 4; ++r) {
    int c = t + 256 * r;
    if (c < C_N) {
      float prod = lamr[r] * sr[r];
      float rcv = prod - SIGMA_C * mu;
      rc[c] = rcv; rp[c] = rpr[r];
      wbuf[c] = lamr[r] / sr[r];
      float vv = lamr[r] + (lamr[r] * rpr[r] - rcv) / sr[r];
      vs[c] = vv; vsum += vv;
    }
  }
  float S_all = bsum256(vsum, red);  // internal barriers also publish vs[]

  float vt[10];
#pragma unroll
  for (int i = 0; i < 10; ++i) vt[i] = vs[tsh[i]];
  float S_tgt = 0.f;
#pragma unroll
  for (int i = 0; i < 10; ++i) S_tgt += vt[i];
  float S_gen = S_all - S_tgt;
  __syncthreads();  // all cross-reads of vs done before in-place scatter

#pragma unroll
  for (int r = 0; r < 4; ++r) {
    int c = t + 256 * r;
    if (c < C_N) {
      int rk = -1;
#pragma unroll
      for (int i = 0; i < 10; ++i) if (c == tsh[i]) rk = i;
      float vc = vs[c];
      float u;
      if (rk < 0)        u = vc;
      else if (rk == 0)  u = -vt[1];
      else if (rk < 9)   u = vc - vt[rk + 1];
      else               u = vc - S_gen;
      vs[c] = u;
    }
  }
  __syncthreads();

  {
    float acc = 0.f;
#pragma unroll 4
    for (int c = 0; c < C_N; ++c) acc += vs[c] * W[c * F_N + t];
    rhs[t] = -(2.f * zs[t] - 2.f * feats[b * F_N + t] + acc);
  }
}

// ---------------------------------------------------------------------------
// K_C: M64 = (double)(2I + X^T diag(w) X), lower 64x64 tiles.  grid = B*10.
__global__ __launch_bounds__(256) void k_syrk(float* wsf) {
  int blk = blockIdx.x;
  int b = blk / 10, tile = blk % 10;
  const int TI[10] = {0,1,1,2,2,2,3,3,3,3};
  const int TJ[10] = {0,0,1,0,1,2,0,1,2,3};
  int ti = TI[tile], tj = TJ[tile];
  int t = threadIdx.x;
  int tx = t & 15, ty = t >> 4;
  __shared__ __align__(16) float As[64][64];  // w-weighted (row/i side)
  __shared__ __align__(16) float Bs[64][64];  // raw (col/k side)
  const float* X  = wsf + OFF_X  + (size_t)b * 256000;
  const float* wv = wsf + OFF_WV + b * C_N;
  float acc[4][4] = {{0.f}};
  int f4 = t & 15, jr0 = t >> 4;
  for (int cc = 0; cc < C_N; cc += 64) {
    __syncthreads();
#pragma unroll
    for (int rep = 0; rep < 4; ++rep) {
      int j = jr0 + rep * 16;
      int c = cc + j;
      float wj = (c < C_N) ? wv[c] : 0.f;
      float4 v = (c < C_N) ? *(const float4*)&X[(size_t)c * F_N + ti * 64 + f4 * 4]
                           : make_float4(0.f, 0.f, 0.f, 0.f);
      float4 u;
      if (tj == ti) u = v;
      else u = (c < C_N) ? *(const float4*)&X[(size_t)c * F_N + tj * 64 + f4 * 4]
                         : make_float4(0.f, 0.f, 0.f, 0.f);
      float4 vw = make_float4(wj * v.x, wj * v.y, wj * v.z, wj * v.w);
      *(float4*)&As[j][f4 * 4] = vw;
      *(float4*)&Bs[j][f4 * 4] = u;
    }
    __syncthreads();
#pragma unroll 4
    for (int j = 0; j < 64; ++j) {
      float4 a4 = *(const float4*)&As[j][tx * 4];
      float4 b4 = *(const float4*)&Bs[j][ty * 4];
      acc[0][0] += a4.x * b4.x; acc[0][1] += a4.x * b4.y; acc[0][2] += a4.x * b4.z; acc[0][3] += a4.x * b4.w;
      acc[1][0] += a4.y * b4.x; acc[1][1] += a4.y * b4.y; acc[1][2] += a4.y * b4.z; acc[1][3] += a4.y * b4.w;
      acc[2][0] += a4.z * b4.x; acc[2][1] += a4.z * b4.y; acc[2][2] += a4.z * b4.z; acc[2][3] += a4.z * b4.w;
      acc[3][0] += a4.w * b4.x; acc[3][1] += a4.w * b4.y; acc[3][2] += a4.w * b4.z; acc[3][3] += a4.w * b4.w;
    }
  }
  double* M64 = (double*)(wsf + OFF_M64) + (size_t)b * 65536;
#pragma unroll
  for (int e = 0; e < 4; ++e) {
    int i = ti * 64 + tx * 4 + e;
    int k0 = tj * 64 + ty * 4;
#pragma unroll
    for (int q = 0; q < 4; ++q) {
      float v = acc[e][q] + ((i == k0 + q) ? 2.f : 0.f);
      M64[(size_t)i * F_N + k0 + q] = (double)v;
    }
  }
}

// ---------------------------------------------------------------------------
// K_D v4: f64 LDL^T, NB=16 (R6-proven algebra, a[16]/x[16] = 32 VGPR ->
// fits the 64-VGPR cap hipcc imposes on 1024t blocks; R8/R9's NB=32 a[32]
// spilled), 1024 threads (phase-c sweeps 29->19, 4 waves/SIMD vs R6's 2).
// Then unit-L solves + D-divide (1024t maps, proven in R8/R9).
__global__ __launch_bounds__(1024, 4) void k_chol(float* wsf) {
  int b = blockIdx.x, t = threadIdx.x;
  double* M = (double*)(wsf + OFF_M64) + (size_t)b * 65536;
  __shared__ double Sm[8464];
  double* Db   = Sm;          // [16][17]
  double* invd = Sm + 272;    // [16]
  double* Pb   = Sm + 304;    // [240][17] scaled L
  double* Pu   = Sm + 4384;   // [240][17] u = L*d
  __shared__ double yv[256];
  __shared__ double red2[16 * 65];

  for (int p = 0; p < 16; ++p) {
    int p0 = p * 16, p1 = p0 + 16, nb = 256 - p1;

    // phase a: 16x16 LDL^T diag block, lanes 0..15, rows in registers
    if (t < 16) {
      int l = t;
      double a[16];
#pragma unroll
      for (int q = 0; q < 16; ++q) a[q] = M[(size_t)(p0 + l) * F_N + p0 + q];
#pragma unroll
      for (int j = 0; j < 16; ++j) {
        double d = __shfl(a[j], j);
        double dc = (fabs(d) < 1e-30) ? (d < 0.0 ? -1e-30 : 1e-30) : d;
        double inv = 1.0 / dc;
        if (l == j) a[j] = dc;
        else if (l > j) a[j] *= inv;
#pragma unroll
        for (int k = j + 1; k < 16; ++k) {
          double lkj = __shfl(a[j], k);   // L[k][j]
          if (l >= k) a[k] -= a[j] * (lkj * dc);
        }
      }
#pragma unroll
      for (int q = 0; q < 16; ++q) {
        M[(size_t)(p0 + l) * F_N + p0 + q] = a[q];
        Db[l * 17 + q] = a[q];
      }
      invd[l] = 1.0 / a[l];
    }
    __syncthreads();

    // phase b: panel rows below (one row per thread); store L and u=L*d
    if (t < nb) {
      int r = p1 + t;
      double x[16];
#pragma unroll
      for (int q = 0; q < 16; ++q) x[q] = M[(size_t)r * F_N + p0 + q];
#pragma unroll
      for (int k = 0; k < 16; ++k) {
        double uk = x[k];
#pragma unroll
        for (int j = k + 1; j < 16; ++j) x[j] -= uk * Db[j * 17 + k];
        x[k] = uk * invd[k];
        Pu[t * 17 + k] = uk;
        Pb[t * 17 + k] = x[k];
      }
#pragma unroll
      for (int q = 0; q < 16; ++q) M[(size_t)r * F_N + p0 + q] = x[q];
    }
    __syncthreads();

    // phase c: trailing update A -= L * D * L^T (4x4 register tiles, lower)
    int nt4 = nb >> 2;
    int Ntile = nt4 * (nt4 + 1) / 2;
    for (int tt = t; tt < Ntile; tt += 1024) {
      float fsq = sqrtf((float)(8 * tt + 1));
      int ti = (int)((fsq - 1.f) * 0.5f);
      while ((ti + 1) * (ti + 2) / 2 <= tt) ++ti;
      while (ti * (ti + 1) / 2 > tt) --ti;
      int tk = tt - ti * (ti + 1) / 2;
      int ib = ti * 4, kb = tk * 4;
      double* m0 = M + (size_t)(p1 + ib) * F_N + p1 + kb;
      double a00 = m0[0],   a01 = m0[1],   a02 = m0[2],   a03 = m0[3];
      double a10 = m0[256], a11 = m0[257], a12 = m0[258], a13 = m0[259];
      double a20 = m0[512], a21 = m0[513], a22 = m0[514], a23 = m0[515];
      double a30 = m0[768], a31 = m0[769], a32 = m0[770], a33 = m0[771];
#pragma unroll
      for (int j = 0; j < 16; ++j) {
        double A0 = Pb[(ib + 0) * 17 + j], A1 = Pb[(ib + 1) * 17 + j];
        double A2 = Pb[(ib + 2) * 17 + j], A3 = Pb[(ib + 3) * 17 + j];
        double B0 = Pu[(kb + 0) * 17 + j], B1 = Pu[(kb + 1) * 17 + j];
        double B2 = Pu[(kb + 2) * 17 + j], B3 = Pu[(kb + 3) * 17 + j];
        a00 -= A0 * B0; a01 -= A0 * B1; a02 -= A0 * B2; a03 -= A0 * B3;
        a10 -= A1 * B0; a11 -= A1 * B1; a12 -= A1 * B2; a13 -= A1 * B3;
        a20 -= A2 * B0; a21 -= A2 * B1; a22 -= A2 * B2; a23 -= A2 * B3;
        a30 -= A3 * B0; a31 -= A3 * B1; a32 -= A3 * B2; a33 -= A3 * B3;
      }
      m0[0]   = a00; m0[1]   = a01; m0[2]   = a02; m0[3]   = a03;
      m0[256] = a10; m0[257] = a11; m0[258] = a12; m0[259] = a13;
      m0[512] = a20; m0[513] = a21; m0[514] = a22; m0[515] = a23;
      m0[768] = a30; m0[769] = a31; m0[770] = a32; m0[771] = a33;
    }
    __syncthreads();
  }

  // ---- triangular solves (unit L), D-divide in the middle ----
  {
    const float* rhs = wsf + OFF_RHS + (size_t)b * F_N;
    if (t < 256) yv[t] = (double)rhs[t];
  }
  __syncthreads();
  double* Ls = Sm;  // [64][66] = 4224 doubles <= 8464 (Db/Pb/Pu dead)

  for (int blk = 0; blk < 4; ++blk) {
    int r0 = blk * 64;
    {
      int row = t >> 4, c4 = (t & 15) * 4;
#pragma unroll
      for (int q = 0; q < 4; ++q)
        Ls[row * 66 + c4 + q] = M[(size_t)(r0 + row) * F_N + r0 + c4 + q];
    }
    __syncthreads();
    if (t < 64) {
      int l = t;
      double acc = yv[r0 + l];
#pragma unroll
      for (int j = 0; j < 64; ++j) {
        double xj = __shfl(acc, j);
        if (l > j) acc -= Ls[l * 66 + j] * xj;
      }
      yv[r0 + l] = acc;
    }
    __syncthreads();
    int nrem = 192 - blk * 64;
    if (t < nrem) {
      int r = r0 + 64 + t;
      double a2 = 0.0;
#pragma unroll 4
      for (int j = 0; j < 64; ++j) a2 += M[(size_t)r * F_N + r0 + j] * yv[r0 + j];
      yv[r] -= a2;
    }
    __syncthreads();
  }

  if (t < 256) yv[t] = yv[t] / M[(size_t)t * F_N + t];
  __syncthreads();

  for (int blk = 3; blk >= 0; --blk) {
    int r0 = blk * 64, r1 = r0 + 64;
    if (blk < 3) {
      int i = r0 + (t & 63), g = t >> 6;   // 16 groups of 64
      double part = 0.0;
      for (int j = r1 + g; j < 256; j += 16) part += M[(size_t)j * F_N + i] * yv[j];
      red2[g * 65 + (t & 63)] = part;
      __syncthreads();
      if (t < 64) {
        double tot = 0.0;
#pragma unroll
        for (int g2 = 0; g2 < 16; ++g2) tot += red2[g2 * 65 + t];
        yv[r0 + t] -= tot;
      }
      __syncthreads();
    }
    {
      int row = t >> 4, c4 = (t & 15) * 4;
#pragma unroll
      for (int q = 0; q < 4; ++q)
        Ls[row * 66 + c4 + q] = M[(size_t)(r0 + row) * F_N + r0 + c4 + q];
    }
    __syncthreads();
    if (t < 64) {
      int l = t;
      double acc = yv[r0 + l];
#pragma unroll
      for (int j = 63; j >= 0; --j) {
        double xj = __shfl(acc, j);
        if (l < j) acc -= Ls[j * 66 + l] * xj;
      }
      yv[r0 + l] = acc;
    }
    __syncthreads();
  }

  if (t < 256) (wsf + OFF_DZ)[(size_t)b * F_N + t] = (float)yv[t];
}

// ---------------------------------------------------------------------------
// K_E: apply the 20th update and compute loss[b] = sum_k (feats - z)^2
__global__ __launch_bounds__(256) void k_final(const float* __restrict__ feats,
                                               float* wsf, float* __restrict__ out) {
  int b = blockIdx.x, t = threadIdx.x;
  __shared__ float zs[256], dzs[256];
  __shared__ __align__(16) float ys[1000];
  __shared__ float red[4];
  const float* WT = wsf + OFF_WT;
  const int* ai  = (const int*)(wsf + OFF_AI) + b * C_N;
  const int* bi  = (const int*)(wsf + OFF_BI) + b * C_N;
  const float* lam = wsf + OFF_LAM + b * C_N;
  const float* s   = wsf + OFF_S   + b * C_N;
  const float* rp  = wsf + OFF_RP  + b * C_N;
  const float* rc  = wsf + OFF_RC  + b * C_N;
  const float* z   = wsf + OFF_Z   + b * F_N;
  const float* dz  = wsf + OFF_DZ  + b * F_N;

  zs[t] = z[t];
  dzs[t] = dz[t];
  __syncthreads();
  if (t < 250) {
    float4 acc = make_float4(0.f, 0.f, 0.f, 0.f);
    const float4* WT4 = (const float4*)WT;
#pragma unroll 4
    for (int k = 0; k < 256; ++k) {
      float zk = dzs[k];
      float4 w4 = WT4[k * 250 + t];
      acc.x += zk * w4.x; acc.y += zk * w4.y; acc.z += zk * w4.z; acc.w += zk * w4.w;
    }
    *(float4*)&ys[4 * t] = acc;
  }
  __syncthreads();
  float amin = BIGV;
#pragma unroll
  for (int r = 0; r < 4; ++r) {
    int c = t + 256 * r;
    if (c < C_N) {
      float lv = lam[c], sv = s[c], rpv = rp[c], rcv = rc[c];
      float g = ys[ai[c]] - ys[bi[c]];
      float dsv = -rpv - g;
      float dlv = -(rcv + lv * dsv) / sv;
      if (dsv < 0.f) amin = fminf(amin, -sv / dsv);
      if (dlv < 0.f) amin = fminf(amin, -lv / dlv);
    }
  }
  float am = bmin256(amin, red);
  float alpha = fminf(1.f, 0.99f * am);
  float zf = zs[t] + alpha * dzs[t];
  float d = feats[b * F_N + t] - zf;
  float loss = bsum256(d * d, red);
  if (t == 0) out[b] = loss;
}

// ---------------------------------------------------------------------------
extern "C" void kernel_launch(void* const* d_in, const int* in_sizes, int n_in,
                              void* d_out, int out_size, void* d_ws, size_t ws_size,
                              hipStream_t stream) {
  (void)in_sizes; (void)n_in; (void)out_size; (void)ws_size;
  const float* feats = (const float*)d_in[1];
  const int*   tg    = (const int*)d_in[3];
  const float* W     = (const float*)d_in[4];
  const float* bias  = (const float*)d_in[5];
  const float* marg  = (const float*)d_in[6];
  float* wsf = (float*)d_ws;
  float* out = (float*)d_out;

  k_transpose<<<64, 256, 0, stream>>>(W, wsf + OFF_WT);
  k_setup<<<B_N, 256, 0, stream>>>(tg, bias, feats, marg, wsf);
  k_buildX<<<B_N * 8, 256, 0, stream>>>(W, wsf);   // once: X is iteration-invariant
  for (int it = 0; it < ITERS_N; ++it) {
    k_iter_pre<<<B_N, 256, 0, stream>>>(W, feats, tg, wsf, it > 0 ? 1 : 0);
    k_syrk<<<B_N * 10, 256, 0, stream>>>(wsf);
    k_chol<<<B_N, 1024, 0, stream>>>(wsf);
  }
  k_final<<<B_N, 256, 0, stream>>>(feats, wsf, out);
}